// Round 1
// baseline (15753.181 us; speedup 1.0000x reference)
//
#include <hip/hip_runtime.h>
#include <math.h>

#define B 512
#define H 256
#define L 256
#define T 64
#define V 128
#define LAYERS 2
#define SOS 0
#define R 4            // batch rows per block
#define NBLK (B / R)   // 128 blocks

// ---- workspace layout (floats) ----
#define OFF_ATTN_WT 0                                 // [2H][L]   attn_wT[k][l]
#define OFF_COMB_WT (OFF_ATTN_WT + 2 * H * L)          // [2H][H]   comb_wT[k][h]
#define OFF_GRU_IHT (OFF_COMB_WT + 2 * H * H)          // [2][H][3H] w_ihT[layer][k][j]
#define OFF_GRU_HHT (OFF_GRU_IHT + LAYERS * H * 3 * H) // [2][H][3H]
#define OFF_OUT_WT  (OFF_GRU_HHT + LAYERS * H * 3 * H) // [H][V]    out_wT[k][v]
#define WS_FLOATS   (OFF_OUT_WT + H * V)               // 1,081,344 floats ~= 4.33 MB

__device__ __forceinline__ float sigmoidf(float v) {
    return 1.f / (1.f + __expf(-v));
}

// One-time transpose of all weight matrices into ws so the main kernel's
// per-k weight loads are lane-coalesced (consecutive lanes = consecutive
// output columns).
__global__ void prep_transpose(const float* __restrict__ attn_w,
                               const float* __restrict__ comb_w,
                               const float* __restrict__ gru_w_ih,
                               const float* __restrict__ gru_w_hh,
                               const float* __restrict__ out_w,
                               float* __restrict__ ws) {
    int i = blockIdx.x * blockDim.x + threadIdx.x;
    int stride = gridDim.x * blockDim.x;
    for (int idx = i; idx < 2 * H * L; idx += stride) {
        int k = idx / L, l = idx % L;
        ws[OFF_ATTN_WT + idx] = attn_w[l * (2 * H) + k];
    }
    for (int idx = i; idx < 2 * H * H; idx += stride) {
        int k = idx / H, h = idx % H;
        ws[OFF_COMB_WT + idx] = comb_w[h * (2 * H) + k];
    }
    for (int idx = i; idx < LAYERS * H * 3 * H; idx += stride) {
        int layer = idx / (H * 3 * H);
        int rem = idx % (H * 3 * H);
        int k = rem / (3 * H), j = rem % (3 * H);
        ws[OFF_GRU_IHT + idx] = gru_w_ih[layer * (3 * H * H) + j * H + k];
        ws[OFF_GRU_HHT + idx] = gru_w_hh[layer * (3 * H * H) + j * H + k];
    }
    for (int idx = i; idx < H * V; idx += stride) {
        int k = idx / V, v = idx % V;
        ws[OFF_OUT_WT + idx] = out_w[v * H + k];
    }
}

// Each block owns R=4 batch rows for the full 64-step rollout.
// All per-row state (h, e, aw, applied, g) lives in LDS; no cross-block
// communication -> single launch, no grid sync.
__global__ __launch_bounds__(256) void decoder_kernel(
    const float* __restrict__ x,       // [B][H][1][L]
    const int* __restrict__ y,         // [B][T]
    const float* __restrict__ emb,     // [V][H]
    const float* __restrict__ attn_b,  // [L]
    const float* __restrict__ comb_b,  // [H]
    const float* __restrict__ gru_b_ih,// [2][3H]
    const float* __restrict__ gru_b_hh,// [2][3H]
    const float* __restrict__ out_b,   // [V]
    const float* __restrict__ ws,
    float* __restrict__ out) {
    __shared__ __align__(16) float sh_h[LAYERS][R][H];
    __shared__ __align__(16) float sh_e[R][H];
    __shared__ __align__(16) float sh_aw[R][L];  // scores->weights; reused as logits[R][V]
    __shared__ __align__(16) float sh_ap[R][H];  // applied
    __shared__ __align__(16) float sh_g[R][H];
    __shared__ int sh_tok[R];

    const int tid = threadIdx.x;     // 0..255, used as l / h / j index
    const int b0 = blockIdx.x * R;
    const int wave = tid >> 6;       // 0..3  (one wave per row in reductions)
    const int lane = tid & 63;

    const float* attn_wT = ws + OFF_ATTN_WT;
    const float* comb_wT = ws + OFF_COMB_WT;
    const float* ihT = ws + OFF_GRU_IHT;
    const float* hhT = ws + OFF_GRU_HHT;
    const float* out_wT = ws + OFF_OUT_WT;

    // h0 = zeros
    for (int l = 0; l < LAYERS; ++l)
#pragma unroll
        for (int r = 0; r < R; ++r) sh_h[l][r][tid] = 0.f;
    __syncthreads();

    for (int t = 0; t < T; ++t) {
        // ---- A: token + embedding gather ----
        if (tid < R) {
            int b = b0 + tid;
            sh_tok[tid] = (t == 0) ? SOS : y[b * T + (t - 1)];
        }
        __syncthreads();
#pragma unroll
        for (int r = 0; r < R; ++r) sh_e[r][tid] = emb[sh_tok[r] * H + tid];
        __syncthreads();

        // ---- B: attn scores: [e, h0] @ attn_w.T + b   (thread = output l) ----
        {
            float ab = attn_b[tid];
            float a0 = ab, a1 = ab, a2 = ab, a3 = ab;
            for (int k = 0; k < H; k += 4) {
                float w0 = attn_wT[(k + 0) * L + tid];
                float w1 = attn_wT[(k + 1) * L + tid];
                float w2 = attn_wT[(k + 2) * L + tid];
                float w3 = attn_wT[(k + 3) * L + tid];
                float4 e0 = *(const float4*)&sh_e[0][k];
                float4 e1 = *(const float4*)&sh_e[1][k];
                float4 e2 = *(const float4*)&sh_e[2][k];
                float4 e3 = *(const float4*)&sh_e[3][k];
                a0 += e0.x * w0 + e0.y * w1 + e0.z * w2 + e0.w * w3;
                a1 += e1.x * w0 + e1.y * w1 + e1.z * w2 + e1.w * w3;
                a2 += e2.x * w0 + e2.y * w1 + e2.z * w2 + e2.w * w3;
                a3 += e3.x * w0 + e3.y * w1 + e3.z * w2 + e3.w * w3;
            }
            for (int k = 0; k < H; k += 4) {
                float w0 = attn_wT[(H + k + 0) * L + tid];
                float w1 = attn_wT[(H + k + 1) * L + tid];
                float w2 = attn_wT[(H + k + 2) * L + tid];
                float w3 = attn_wT[(H + k + 3) * L + tid];
                float4 h0v = *(const float4*)&sh_h[0][0][k];
                float4 h1v = *(const float4*)&sh_h[0][1][k];
                float4 h2v = *(const float4*)&sh_h[0][2][k];
                float4 h3v = *(const float4*)&sh_h[0][3][k];
                a0 += h0v.x * w0 + h0v.y * w1 + h0v.z * w2 + h0v.w * w3;
                a1 += h1v.x * w0 + h1v.y * w1 + h1v.z * w2 + h1v.w * w3;
                a2 += h2v.x * w0 + h2v.y * w1 + h2v.z * w2 + h2v.w * w3;
                a3 += h3v.x * w0 + h3v.y * w1 + h3v.z * w2 + h3v.w * w3;
            }
            sh_aw[0][tid] = a0;
            sh_aw[1][tid] = a1;
            sh_aw[2][tid] = a2;
            sh_aw[3][tid] = a3;
        }
        __syncthreads();

        // ---- softmax over L (wave r handles row r) + write attns output ----
        {
            int r = wave;
            float s0 = sh_aw[r][lane], s1 = sh_aw[r][lane + 64];
            float s2 = sh_aw[r][lane + 128], s3 = sh_aw[r][lane + 192];
            float m = fmaxf(fmaxf(s0, s1), fmaxf(s2, s3));
            for (int off = 32; off; off >>= 1) m = fmaxf(m, __shfl_xor(m, off));
            float e0 = __expf(s0 - m), e1 = __expf(s1 - m);
            float e2 = __expf(s2 - m), e3 = __expf(s3 - m);
            float s = e0 + e1 + e2 + e3;
            for (int off = 32; off; off >>= 1) s += __shfl_xor(s, off);
            float inv = 1.f / s;
            e0 *= inv; e1 *= inv; e2 *= inv; e3 *= inv;
            sh_aw[r][lane] = e0;
            sh_aw[r][lane + 64] = e1;
            sh_aw[r][lane + 128] = e2;
            sh_aw[r][lane + 192] = e3;
            size_t base = (size_t)B * V * T + (size_t)(b0 + r) * T * L + (size_t)t * L;
            out[base + lane] = e0;
            out[base + lane + 64] = e1;
            out[base + lane + 128] = e2;
            out[base + lane + 192] = e3;
        }
        __syncthreads();

        // ---- C: applied[r][h] = sum_l aw[r][l] * enc[b][l][h] = x[b][h][l] ----
        {
#pragma unroll
            for (int r = 0; r < R; ++r) {
                const float* xrow = x + ((size_t)(b0 + r) * H + tid) * L;
                float a = 0.f;
                for (int l = 0; l < L; l += 4) {
                    float4 xv = *(const float4*)(xrow + l);
                    float4 wv = *(const float4*)&sh_aw[r][l];
                    a += xv.x * wv.x + xv.y * wv.y + xv.z * wv.z + xv.w * wv.w;
                }
                sh_ap[r][tid] = a;
            }
        }
        __syncthreads();

        // ---- D: g = relu([applied, e] @ comb_w.T + b)   (thread = output h) ----
        {
            float cb = comb_b[tid];
            float a0 = cb, a1 = cb, a2 = cb, a3 = cb;
            for (int k = 0; k < H; k += 4) {
                float w0 = comb_wT[(k + 0) * H + tid];
                float w1 = comb_wT[(k + 1) * H + tid];
                float w2 = comb_wT[(k + 2) * H + tid];
                float w3 = comb_wT[(k + 3) * H + tid];
                float4 p0 = *(const float4*)&sh_ap[0][k];
                float4 p1 = *(const float4*)&sh_ap[1][k];
                float4 p2 = *(const float4*)&sh_ap[2][k];
                float4 p3 = *(const float4*)&sh_ap[3][k];
                a0 += p0.x * w0 + p0.y * w1 + p0.z * w2 + p0.w * w3;
                a1 += p1.x * w0 + p1.y * w1 + p1.z * w2 + p1.w * w3;
                a2 += p2.x * w0 + p2.y * w1 + p2.z * w2 + p2.w * w3;
                a3 += p3.x * w0 + p3.y * w1 + p3.z * w2 + p3.w * w3;
            }
            for (int k = 0; k < H; k += 4) {
                float w0 = comb_wT[(H + k + 0) * H + tid];
                float w1 = comb_wT[(H + k + 1) * H + tid];
                float w2 = comb_wT[(H + k + 2) * H + tid];
                float w3 = comb_wT[(H + k + 3) * H + tid];
                float4 e0 = *(const float4*)&sh_e[0][k];
                float4 e1 = *(const float4*)&sh_e[1][k];
                float4 e2 = *(const float4*)&sh_e[2][k];
                float4 e3 = *(const float4*)&sh_e[3][k];
                a0 += e0.x * w0 + e0.y * w1 + e0.z * w2 + e0.w * w3;
                a1 += e1.x * w0 + e1.y * w1 + e1.z * w2 + e1.w * w3;
                a2 += e2.x * w0 + e2.y * w1 + e2.z * w2 + e2.w * w3;
                a3 += e3.x * w0 + e3.y * w1 + e3.z * w2 + e3.w * w3;
            }
            sh_g[0][tid] = fmaxf(a0, 0.f);
            sh_g[1][tid] = fmaxf(a1, 0.f);
            sh_g[2][tid] = fmaxf(a2, 0.f);
            sh_g[3][tid] = fmaxf(a3, 0.f);
        }
        __syncthreads();

        // ---- E/F: 2-layer GRU (thread = hidden unit j; all 3 gates local) ----
        for (int layer = 0; layer < LAYERS; ++layer) {
            const float(*xin)[H] =
                (layer == 0) ? (const float(*)[H])sh_g : (const float(*)[H])sh_h[0];
            const float(*hid)[H] = (const float(*)[H])sh_h[layer];
            const float* wih = ihT + layer * (H * 3 * H);
            const float* whh = hhT + layer * (H * 3 * H);
            float accR[R] = {0, 0, 0, 0}, accZ[R] = {0, 0, 0, 0}, accN[R] = {0, 0, 0, 0};
            float accRh[R] = {0, 0, 0, 0}, accZh[R] = {0, 0, 0, 0}, accNh[R] = {0, 0, 0, 0};
            for (int k = 0; k < H; k += 4) {
                float4 xv[R], hv[R];
#pragma unroll
                for (int r = 0; r < R; ++r) {
                    xv[r] = *(const float4*)&xin[r][k];
                    hv[r] = *(const float4*)&hid[r][k];
                }
#pragma unroll
                for (int kk = 0; kk < 4; ++kk) {
                    const float* wp = wih + (size_t)(k + kk) * (3 * H) + tid;
                    const float* vp = whh + (size_t)(k + kk) * (3 * H) + tid;
                    float wr = wp[0], wz = wp[H], wn = wp[2 * H];
                    float vr = vp[0], vz = vp[H], vn = vp[2 * H];
#pragma unroll
                    for (int r = 0; r < R; ++r) {
                        float xs = ((const float*)&xv[r])[kk];
                        float hs = ((const float*)&hv[r])[kk];
                        accR[r] += xs * wr;
                        accZ[r] += xs * wz;
                        accN[r] += xs * wn;
                        accRh[r] += hs * vr;
                        accZh[r] += hs * vz;
                        accNh[r] += hs * vn;
                    }
                }
            }
            float bir = gru_b_ih[layer * 3 * H + tid];
            float biz = gru_b_ih[layer * 3 * H + H + tid];
            float bin_ = gru_b_ih[layer * 3 * H + 2 * H + tid];
            float bhr = gru_b_hh[layer * 3 * H + tid];
            float bhz = gru_b_hh[layer * 3 * H + H + tid];
            float bhn = gru_b_hh[layer * 3 * H + 2 * H + tid];
            float hnew[R];
#pragma unroll
            for (int r = 0; r < R; ++r) {
                float rr = sigmoidf(accR[r] + bir + accRh[r] + bhr);
                float zz = sigmoidf(accZ[r] + biz + accZh[r] + bhz);
                float nn = tanhf(accN[r] + bin_ + rr * (accNh[r] + bhn));
                hnew[r] = (1.f - zz) * nn + zz * hid[r][tid];
            }
            __syncthreads();  // all reads of old h[layer] / xin complete
#pragma unroll
            for (int r = 0; r < R; ++r) sh_h[layer][r][tid] = hnew[r];
            __syncthreads();
        }

        // ---- G: logits + log_softmax ----
        {
            if (tid < V) {
                float ob = out_b[tid];
                float a0 = ob, a1 = ob, a2 = ob, a3 = ob;
                for (int k = 0; k < H; k += 4) {
                    float w0 = out_wT[(k + 0) * V + tid];
                    float w1 = out_wT[(k + 1) * V + tid];
                    float w2 = out_wT[(k + 2) * V + tid];
                    float w3 = out_wT[(k + 3) * V + tid];
                    float4 h0v = *(const float4*)&sh_h[1][0][k];
                    float4 h1v = *(const float4*)&sh_h[1][1][k];
                    float4 h2v = *(const float4*)&sh_h[1][2][k];
                    float4 h3v = *(const float4*)&sh_h[1][3][k];
                    a0 += h0v.x * w0 + h0v.y * w1 + h0v.z * w2 + h0v.w * w3;
                    a1 += h1v.x * w0 + h1v.y * w1 + h1v.z * w2 + h1v.w * w3;
                    a2 += h2v.x * w0 + h2v.y * w1 + h2v.z * w2 + h2v.w * w3;
                    a3 += h3v.x * w0 + h3v.y * w1 + h3v.z * w2 + h3v.w * w3;
                }
                sh_aw[0][tid] = a0;  // reuse sh_aw as logits[R][V]
                sh_aw[1][tid] = a1;
                sh_aw[2][tid] = a2;
                sh_aw[3][tid] = a3;
            }
            __syncthreads();
            {
                int r = wave;
                float l0 = sh_aw[r][lane], l1 = sh_aw[r][lane + 64];
                float m = fmaxf(l0, l1);
                for (int off = 32; off; off >>= 1) m = fmaxf(m, __shfl_xor(m, off));
                float s = __expf(l0 - m) + __expf(l1 - m);
                for (int off = 32; off; off >>= 1) s += __shfl_xor(s, off);
                float lse = m + __logf(s);
                // outs[b][v][t]
                size_t base = (size_t)(b0 + r) * V * T + (size_t)t;
                out[base + (size_t)lane * T] = l0 - lse;
                out[base + (size_t)(lane + 64) * T] = l1 - lse;
            }
        }
        __syncthreads();
    }
}

extern "C" void kernel_launch(void* const* d_in, const int* in_sizes, int n_in,
                              void* d_out, int out_size, void* d_ws, size_t ws_size,
                              hipStream_t stream) {
    const float* x = (const float*)d_in[0];
    const int* y = (const int*)d_in[1];
    const float* emb = (const float*)d_in[2];
    const float* attn_w = (const float*)d_in[3];
    const float* attn_b = (const float*)d_in[4];
    const float* comb_w = (const float*)d_in[5];
    const float* comb_b = (const float*)d_in[6];
    const float* gru_w_ih = (const float*)d_in[7];
    const float* gru_w_hh = (const float*)d_in[8];
    const float* gru_b_ih = (const float*)d_in[9];
    const float* gru_b_hh = (const float*)d_in[10];
    const float* out_w = (const float*)d_in[11];
    const float* out_b = (const float*)d_in[12];
    float* out = (float*)d_out;
    float* ws = (float*)d_ws;

    prep_transpose<<<512, 256, 0, stream>>>(attn_w, comb_w, gru_w_ih, gru_w_hh, out_w, ws);
    decoder_kernel<<<NBLK, 256, 0, stream>>>(x, y, emb, attn_b, comb_b, gru_b_ih,
                                             gru_b_hh, out_b, ws, out);
}

// Round 2
// 5913.845 us; speedup vs baseline: 2.6638x; 2.6638x over previous
//
#include <hip/hip_runtime.h>
#include <math.h>

#define B 512
#define H 256
#define L 256
#define T 64
#define V 128
#define LAYERS 2
#define SOS 0

// ---- workspace layout (in _Float16 elements) ----
// All weights stored f16, k8-blocked: [k8][out][8] -> each lane loads 16B
// (dwordx4), lanes contiguous -> 1KB/wave coalesced.
#define OFF_A 0                      // attn:  [64][256][8]  (K=512 over [e|h])
#define OFF_C 131072                 // comb:  [64][256][8]  (K=512 over [ap|e])
#define OFF_G 262144                 // gru:   [2 layers][6 mats][32][256][8]
#define GRU_LAYER_STRIDE (6 * 65536) // 393216
#define GRU_MAT_STRIDE 65536
#define OFF_O (OFF_G + LAYERS * GRU_LAYER_STRIDE) // out: [32][128][8]
#define WS_HALVES (OFF_O + 32768)    // 1,081,344 halves = 2.16 MB

typedef _Float16 half8 __attribute__((ext_vector_type(8)));
typedef _Float16 half2t __attribute__((ext_vector_type(2)));
typedef float f4v __attribute__((ext_vector_type(4)));

#if __has_builtin(__builtin_nontemporal_load)
#define NT_LOAD(p) __builtin_nontemporal_load(p)
#else
#define NT_LOAD(p) (*(p))
#endif

__device__ __forceinline__ float fdot2(half2t a, half2t b, float c) {
#if __has_builtin(__builtin_amdgcn_fdot2)
    return __builtin_amdgcn_fdot2(a, b, c, false);
#else
    return c + (float)a[0] * (float)b[0] + (float)a[1] * (float)b[1];
#endif
}

union H8 {
    half8 v;
    half2t p[4];
};

__device__ __forceinline__ float sigmoidf_(float v) {
    return 1.f / (1.f + __expf(-v));
}
__device__ __forceinline__ float fast_tanh(float v) {
    v = fminf(fmaxf(v, -15.f), 15.f);
    float e = __expf(-2.f * v);
    return (1.f - e) / (1.f + e);
}

// One-time repack of all weights to f16 k8-blocked layouts in ws.
__global__ void prep_pack(const float* __restrict__ attn_w,
                          const float* __restrict__ comb_w,
                          const float* __restrict__ gru_w_ih,
                          const float* __restrict__ gru_w_hh,
                          const float* __restrict__ out_w,
                          _Float16* __restrict__ ws) {
    int stride = gridDim.x * blockDim.x;
    for (int idx = blockIdx.x * blockDim.x + threadIdx.x; idx < WS_HALVES; idx += stride) {
        float val;
        if (idx < OFF_C) {
            int i = idx & 7, r = idx >> 3;
            int l = r & 255, k8 = r >> 8;
            val = attn_w[l * 512 + k8 * 8 + i];
        } else if (idx < OFF_G) {
            int e = idx - OFF_C;
            int i = e & 7, r = e >> 3;
            int hh = r & 255, k8 = r >> 8;
            val = comb_w[hh * 512 + k8 * 8 + i];
        } else if (idx < OFF_O) {
            int e = idx - OFF_G;
            int layer = e / GRU_LAYER_STRIDE;
            e -= layer * GRU_LAYER_STRIDE;
            int mat = e >> 16;
            e &= 65535;
            int i = e & 7, r = e >> 3;
            int j = r & 255, k8 = r >> 8;
            int k = k8 * 8 + i;
            const float* src = (mat < 3) ? gru_w_ih : gru_w_hh;
            int gate = (mat < 3) ? mat : mat - 3;
            val = src[layer * (768 * 256) + (gate * 256 + j) * 256 + k];
        } else {
            int e = idx - OFF_O;
            int i = e & 7, r = e >> 3;
            int v = r & 127, k8 = r >> 7;
            val = out_w[v * 256 + k8 * 8 + i];
        }
        ws[idx] = (_Float16)val;
    }
}

// 256 blocks x 512 threads. Block owns 2 batch rows; group g = tid>>8 owns
// row b0+g with its 256 threads (4 waves). All LDS activation reads are
// wave-broadcasts (same address) -> conflict-free. Weights stream from L2
// as f16 dwordx4, consumed by v_dot2_f32_f16 with fp32 accumulation.
__global__ __launch_bounds__(512) void decoder_kernel(
    const float* __restrict__ x,        // [B][H][1][L] fp32
    const int* __restrict__ y,          // [B][T]
    const float* __restrict__ emb,      // [V][H]
    const float* __restrict__ attn_b,   // [L]
    const float* __restrict__ comb_b,   // [H]
    const float* __restrict__ gru_b_ih, // [2][3H]
    const float* __restrict__ gru_b_hh, // [2][3H]
    const float* __restrict__ out_b,    // [V]
    const _Float16* __restrict__ wsh,
    float* __restrict__ out) {
    __shared__ __align__(16) _Float16 ehf[2][512];        // [e | h0] f16, scores input
    __shared__ __align__(16) _Float16 hfs[LAYERS][2][256]; // h f16 (dot input)
    __shared__ __align__(16) float h32[LAYERS][2][256];    // h fp32 (blend)
    __shared__ __align__(16) _Float16 apf[2][256];         // applied f16
    __shared__ __align__(16) _Float16 gf[2][256];          // comb output f16
    __shared__ __align__(16) float aw32[2][256];           // attn weights fp32
    __shared__ __align__(16) float sc[2][256];             // raw scores
    __shared__ __align__(16) float lg[2][128];             // logits

    const int tid = threadIdx.x;
    const int g = tid >> 8;      // row group 0/1
    const int h = tid & 255;     // output-unit index within group
    const int lane = tid & 63;
    const int wgrp = (tid >> 6) & 3; // wave index within group
    const int b = blockIdx.x * 2 + g;

    const _Float16* AW = wsh + OFF_A;
    const _Float16* CW = wsh + OFF_C;
    const _Float16* OW = wsh + OFF_O;

    // ---- preload biases into registers (constant thread role) ----
    const float ab = attn_b[h];
    const float cb = comb_b[h];
    const float ob = (h < V) ? out_b[h] : 0.f;
    float b_ir[LAYERS], b_iz[LAYERS], b_in[LAYERS], b_hr[LAYERS], b_hz[LAYERS], b_hn[LAYERS];
#pragma unroll
    for (int l = 0; l < LAYERS; ++l) {
        b_ir[l] = gru_b_ih[l * 768 + h];
        b_iz[l] = gru_b_ih[l * 768 + 256 + h];
        b_in[l] = gru_b_ih[l * 768 + 512 + h];
        b_hr[l] = gru_b_hh[l * 768 + h];
        b_hz[l] = gru_b_hh[l * 768 + 256 + h];
        b_hn[l] = gru_b_hh[l * 768 + 512 + h];
    }

    // ---- init state ----
#pragma unroll
    for (int l = 0; l < LAYERS; ++l) {
        h32[l][g][h] = 0.f;
        hfs[l][g][h] = (_Float16)0.f;
    }
    ehf[g][256 + h] = (_Float16)0.f;
    __syncthreads();

    for (int t = 0; t < T; ++t) {
        // ---- embedding gather (tok uniform per group -> scalar load) ----
        int tok = (t == 0) ? SOS : y[b * T + (t - 1)];
        ehf[g][h] = (_Float16)emb[tok * H + h];
        __syncthreads();

        // ---- attn scores: thread = output l; K=512 over [e|h0] ----
        {
            float a0 = 0.f, a1 = 0.f, a2 = 0.f, a3 = 0.f;
            const _Float16* ap = &ehf[g][0];
#pragma unroll 4
            for (int k8 = 0; k8 < 64; ++k8) {
                H8 uw, ua;
                uw.v = *(const half8*)(AW + (((k8 << 8) + h) << 3));
                ua.v = *(const half8*)(ap + (k8 << 3));
                a0 = fdot2(uw.p[0], ua.p[0], a0);
                a1 = fdot2(uw.p[1], ua.p[1], a1);
                a2 = fdot2(uw.p[2], ua.p[2], a2);
                a3 = fdot2(uw.p[3], ua.p[3], a3);
            }
            sc[g][h] = a0 + a1 + a2 + a3 + ab;
        }
        __syncthreads();

        // ---- softmax over L (wave 0 of each group) + attns output ----
        if (wgrp == 0) {
            float s0 = sc[g][lane], s1 = sc[g][lane + 64];
            float s2 = sc[g][lane + 128], s3 = sc[g][lane + 192];
            float m = fmaxf(fmaxf(s0, s1), fmaxf(s2, s3));
            for (int off = 32; off; off >>= 1) m = fmaxf(m, __shfl_xor(m, off));
            float e0 = __expf(s0 - m), e1 = __expf(s1 - m);
            float e2 = __expf(s2 - m), e3 = __expf(s3 - m);
            float s = e0 + e1 + e2 + e3;
            for (int off = 32; off; off >>= 1) s += __shfl_xor(s, off);
            float inv = 1.f / s;
            e0 *= inv; e1 *= inv; e2 *= inv; e3 *= inv;
            aw32[g][lane] = e0;
            aw32[g][lane + 64] = e1;
            aw32[g][lane + 128] = e2;
            aw32[g][lane + 192] = e3;
            size_t base = (size_t)B * V * T + ((size_t)b * T + t) * L;
            out[base + lane] = e0;
            out[base + lane + 64] = e1;
            out[base + lane + 128] = e2;
            out[base + lane + 192] = e3;
        }
        __syncthreads();

        // ---- applied[h] = sum_l aw[l] * x[b][h][l]  (x fp32, nontemporal) ----
        {
            const float* xrow = x + ((size_t)b * H + h) * L;
            float a0 = 0.f, a1 = 0.f;
#pragma unroll 4
            for (int l = 0; l < L; l += 8) {
                f4v x0 = NT_LOAD((const f4v*)(xrow + l));
                f4v x1 = NT_LOAD((const f4v*)(xrow + l + 4));
                float4 w0 = *(const float4*)&aw32[g][l];
                float4 w1 = *(const float4*)&aw32[g][l + 4];
                a0 += x0.x * w0.x + x0.y * w0.y + x0.z * w0.z + x0.w * w0.w;
                a1 += x1.x * w1.x + x1.y * w1.y + x1.z * w1.z + x1.w * w1.w;
            }
            apf[g][h] = (_Float16)(a0 + a1);
        }
        __syncthreads();

        // ---- comb: thread = output h; K=512 over [applied | e] ----
        {
            float a0 = 0.f, a1 = 0.f, a2 = 0.f, a3 = 0.f;
#pragma unroll 4
            for (int k8 = 0; k8 < 32; ++k8) {
                H8 uw, ua;
                uw.v = *(const half8*)(CW + (((k8 << 8) + h) << 3));
                ua.v = *(const half8*)(&apf[g][0] + (k8 << 3));
                a0 = fdot2(uw.p[0], ua.p[0], a0);
                a1 = fdot2(uw.p[1], ua.p[1], a1);
                a2 = fdot2(uw.p[2], ua.p[2], a2);
                a3 = fdot2(uw.p[3], ua.p[3], a3);
            }
#pragma unroll 4
            for (int k8 = 32; k8 < 64; ++k8) {
                H8 uw, ua;
                uw.v = *(const half8*)(CW + (((k8 << 8) + h) << 3));
                ua.v = *(const half8*)(&ehf[g][0] + ((k8 - 32) << 3));
                a0 = fdot2(uw.p[0], ua.p[0], a0);
                a1 = fdot2(uw.p[1], ua.p[1], a1);
                a2 = fdot2(uw.p[2], ua.p[2], a2);
                a3 = fdot2(uw.p[3], ua.p[3], a3);
            }
            gf[g][h] = (_Float16)fmaxf(a0 + a1 + a2 + a3 + cb, 0.f);
        }
        __syncthreads();

        // ---- 2-layer GRU: thread = hidden unit h; 6 dot2 accumulators ----
#pragma unroll
        for (int layer = 0; layer < LAYERS; ++layer) {
            const _Float16* GW = wsh + OFF_G + layer * GRU_LAYER_STRIDE;
            const _Float16* xinp = (layer == 0) ? &gf[g][0] : &hfs[0][g][0];
            const _Float16* hinp = &hfs[layer][g][0];
            float aR = 0.f, aZ = 0.f, aN = 0.f, aRh = 0.f, aZh = 0.f, aNh = 0.f;
#pragma unroll 2
            for (int k8 = 0; k8 < 32; ++k8) {
                H8 xa, ha, w0, w1, w2, w3, w4, w5;
                xa.v = *(const half8*)(xinp + (k8 << 3));
                ha.v = *(const half8*)(hinp + (k8 << 3));
                const int off = ((k8 << 8) + h) << 3;
                w0.v = *(const half8*)(GW + 0 * GRU_MAT_STRIDE + off);
                w1.v = *(const half8*)(GW + 1 * GRU_MAT_STRIDE + off);
                w2.v = *(const half8*)(GW + 2 * GRU_MAT_STRIDE + off);
                w3.v = *(const half8*)(GW + 3 * GRU_MAT_STRIDE + off);
                w4.v = *(const half8*)(GW + 4 * GRU_MAT_STRIDE + off);
                w5.v = *(const half8*)(GW + 5 * GRU_MAT_STRIDE + off);
#pragma unroll
                for (int p = 0; p < 4; ++p) {
                    aR = fdot2(w0.p[p], xa.p[p], aR);
                    aZ = fdot2(w1.p[p], xa.p[p], aZ);
                    aN = fdot2(w2.p[p], xa.p[p], aN);
                    aRh = fdot2(w3.p[p], ha.p[p], aRh);
                    aZh = fdot2(w4.p[p], ha.p[p], aZh);
                    aNh = fdot2(w5.p[p], ha.p[p], aNh);
                }
            }
            float rr = sigmoidf_(aR + b_ir[layer] + aRh + b_hr[layer]);
            float zz = sigmoidf_(aZ + b_iz[layer] + aZh + b_hz[layer]);
            float nn = fast_tanh(aN + b_in[layer] + rr * (aNh + b_hn[layer]));
            float hnew = (1.f - zz) * nn + zz * h32[layer][g][h];
            __syncthreads();  // all dot reads of old h / xin complete
            h32[layer][g][h] = hnew;
            hfs[layer][g][h] = (_Float16)hnew;
            if (layer == 0) ehf[g][256 + h] = (_Float16)hnew;
            __syncthreads();
        }

        // ---- logits: threads h<128 ----
        if (h < V) {
            float a0 = 0.f, a1 = 0.f, a2 = 0.f, a3 = 0.f;
            const _Float16* hp = &hfs[1][g][0];
#pragma unroll 4
            for (int k8 = 0; k8 < 32; ++k8) {
                H8 uw, ua;
                uw.v = *(const half8*)(OW + (((k8 << 7) + h) << 3));
                ua.v = *(const half8*)(hp + (k8 << 3));
                a0 = fdot2(uw.p[0], ua.p[0], a0);
                a1 = fdot2(uw.p[1], ua.p[1], a1);
                a2 = fdot2(uw.p[2], ua.p[2], a2);
                a3 = fdot2(uw.p[3], ua.p[3], a3);
            }
            lg[g][h] = a0 + a1 + a2 + a3 + ob;
        }
        __syncthreads();

        // ---- log_softmax over V (wave 0 of each group) + outs output ----
        if (wgrp == 0) {
            float l0 = lg[g][lane], l1 = lg[g][lane + 64];
            float m = fmaxf(l0, l1);
            for (int off = 32; off; off >>= 1) m = fmaxf(m, __shfl_xor(m, off));
            float s = __expf(l0 - m) + __expf(l1 - m);
            for (int off = 32; off; off >>= 1) s += __shfl_xor(s, off);
            float lse = m + __logf(s);
            size_t base = (size_t)b * V * T + (size_t)t;
            out[base + (size_t)lane * T] = l0 - lse;
            out[base + (size_t)(lane + 64) * T] = l1 - lse;
        }
        __syncthreads();
    }
}

extern "C" void kernel_launch(void* const* d_in, const int* in_sizes, int n_in,
                              void* d_out, int out_size, void* d_ws, size_t ws_size,
                              hipStream_t stream) {
    const float* x = (const float*)d_in[0];
    const int* y = (const int*)d_in[1];
    const float* emb = (const float*)d_in[2];
    const float* attn_w = (const float*)d_in[3];
    const float* attn_b = (const float*)d_in[4];
    const float* comb_w = (const float*)d_in[5];
    const float* comb_b = (const float*)d_in[6];
    const float* gru_w_ih = (const float*)d_in[7];
    const float* gru_w_hh = (const float*)d_in[8];
    const float* gru_b_ih = (const float*)d_in[9];
    const float* gru_b_hh = (const float*)d_in[10];
    const float* out_w = (const float*)d_in[11];
    const float* out_b = (const float*)d_in[12];
    float* out = (float*)d_out;
    _Float16* ws = (_Float16*)d_ws;

    prep_pack<<<512, 256, 0, stream>>>(attn_w, comb_w, gru_w_ih, gru_w_hh, out_w, ws);
    decoder_kernel<<<B / 2, 512, 0, stream>>>(x, y, emb, attn_b, comb_b, gru_b_ih,
                                              gru_b_hh, out_b, ws, out);
}